// Round 10
// baseline (442.352 us; speedup 1.0000x reference)
//
#include <hip/hip_runtime.h>

#define D 128
#define BM 128
#define NWG 256  // workgroups in hist/scatter phases

typedef short short8 __attribute__((ext_vector_type(8)));
typedef float f32x4 __attribute__((ext_vector_type(4)));

__device__ inline unsigned short f2bf_rne(float x) {
    unsigned int b = __float_as_uint(x);
    unsigned int r = (b + 0x7FFFu + ((b >> 16) & 1u)) >> 16;
    return (unsigned short)r;
}
__device__ inline float bf2f(unsigned short h) {
    return __uint_as_float(((unsigned int)h) << 16);
}
__device__ inline void acc_bf(float4& a, ushort4 u) {
    a.x += __uint_as_float((unsigned int)u.x << 16);
    a.y += __uint_as_float((unsigned int)u.y << 16);
    a.z += __uint_as_float((unsigned int)u.z << 16);
    a.w += __uint_as_float((unsigned int)u.w << 16);
}

// ---------------- x -> bf16 plane ----------------
__global__ __launch_bounds__(256) void convert_x(const float* __restrict__ x,
                                                 unsigned short* __restrict__ xb,
                                                 int total) {
    int i = (blockIdx.x * 256 + threadIdx.x) * 8;
    if (i < total) {
        float4 a = *reinterpret_cast<const float4*>(x + i);
        float4 b = *reinterpret_cast<const float4*>(x + i + 4);
        ushort4 u0, u1;
        u0.x = f2bf_rne(a.x); u0.y = f2bf_rne(a.y); u0.z = f2bf_rne(a.z); u0.w = f2bf_rne(a.w);
        u1.x = f2bf_rne(b.x); u1.y = f2bf_rne(b.y); u1.z = f2bf_rne(b.z); u1.w = f2bf_rne(b.w);
        *reinterpret_cast<ushort4*>(xb + i) = u0;
        *reinterpret_cast<ushort4*>(xb + i + 4) = u1;
    }
}

// ---------------- generic scan (256/block) ----------------

__global__ void scan1(const int* __restrict__ in, int* __restrict__ out,
                      int* __restrict__ bsum, int n) {
    __shared__ int s[256];
    int t = threadIdx.x;
    int i = blockIdx.x * 256 + t;
    int v = (i < n) ? in[i] : 0;
    s[t] = v;
    __syncthreads();
    #pragma unroll
    for (int off = 1; off < 256; off <<= 1) {
        int add = (t >= off) ? s[t - off] : 0;
        __syncthreads();
        s[t] += add;
        __syncthreads();
    }
    if (i < n) out[i] = s[t] - v;
    if (t == 255) bsum[blockIdx.x] = s[255];
}

__global__ void scan2(int* __restrict__ bsum, int nb) {
    __shared__ int s[512];
    int t = threadIdx.x;
    int v = (t < nb) ? bsum[t] : 0;
    s[t] = v;
    __syncthreads();
    #pragma unroll
    for (int off = 1; off < 512; off <<= 1) {
        int add = (t >= off) ? s[t - off] : 0;
        __syncthreads();
        s[t] += add;
        __syncthreads();
    }
    if (t < nb) bsum[t] = s[t] - v;
}

__global__ void scan3b(int* __restrict__ out, const int* __restrict__ bsum, int n) {
    int i = blockIdx.x * blockDim.x + threadIdx.x;
    if (i < n) out[i] += bsum[i >> 8];
}

__global__ void set_end(int* __restrict__ row_ptr, int n, int e) {
    row_ptr[n] = e;
}

// ---------------- phase A: bucket histogram + scatter ----------------

__global__ __launch_bounds__(256) void hist_bucket(const int* __restrict__ coli,
                                                   int* __restrict__ hist_t,
                                                   int e, int nbkt, int cpw) {
    __shared__ int hist[512];
    int w = blockIdx.x, tid = threadIdx.x;
    for (int b = tid; b < nbkt; b += 256) hist[b] = 0;
    __syncthreads();
    int i1 = min((w + 1) * cpw, e);
    for (int i = w * cpw + tid; i < i1; i += 256)
        atomicAdd(&hist[coli[i] >> 8], 1);
    __syncthreads();
    for (int b = tid; b < nbkt; b += 256) hist_t[b * NWG + w] = hist[b];
}

__global__ __launch_bounds__(256) void scatter_bucket(const int* __restrict__ rowi,
                                                      const int* __restrict__ coli,
                                                      const int* __restrict__ scanned,
                                                      unsigned int* __restrict__ ebuf,
                                                      int e, int nbkt, int cpw) {
    __shared__ int cur[512];
    int w = blockIdx.x, tid = threadIdx.x;
    for (int b = tid; b < nbkt; b += 256) cur[b] = scanned[b * NWG + w];
    __syncthreads();
    int i1 = min((w + 1) * cpw, e);
    for (int i = w * cpw + tid; i < i1; i += 256) {
        int c = coli[i];
        int b = c >> 8;
        int p = atomicAdd(&cur[b], 1);
        ebuf[p] = ((unsigned int)rowi[i] << 8) | (unsigned int)(c & 255);
    }
}

// ---------------- phase B: per-bucket local CSR ----------------
__global__ __launch_bounds__(256) void csr_bucket(const int* __restrict__ scanned,
                                                  const unsigned int* __restrict__ ebuf,
                                                  int* __restrict__ row_ptr,
                                                  int* __restrict__ srcs,
                                                  int e, int n, int nbkt) {
    __shared__ int cnt[256], s[256], cur[256];
    int b = blockIdx.x, tid = threadIdx.x;
    int S = scanned[b * NWG];
    int Send = (b == nbkt - 1) ? e : scanned[(b + 1) * NWG];
    cnt[tid] = 0;
    __syncthreads();
    for (int i = S + tid; i < Send; i += 256)
        atomicAdd(&cnt[ebuf[i] & 255], 1);
    __syncthreads();
    int v = cnt[tid];
    s[tid] = v;
    __syncthreads();
    #pragma unroll
    for (int off = 1; off < 256; off <<= 1) {
        int add = (tid >= off) ? s[tid - off] : 0;
        __syncthreads();
        s[tid] += add;
        __syncthreads();
    }
    int offx = s[tid] - v;
    int node = b * 256 + tid;
    if (node < n) row_ptr[node] = S + offx;
    cur[tid] = offx;
    __syncthreads();
    for (int i = S + tid; i < Send; i += 256) {
        unsigned int pe = ebuf[i];
        int lc = (int)(pe & 255u);
        int p = S + atomicAdd(&cur[lc], 1);
        srcs[p] = (int)(pe >> 8);
    }
}

// ---------------- mean aggregation over bf16 rows (256B/row) ----------------
__global__ __launch_bounds__(256) void aggregate_mean_bf16(
    const unsigned short* __restrict__ xb, float* __restrict__ mean,
    const int* __restrict__ row_ptr, const int* __restrict__ srcs, int n) {
    int node = blockIdx.x * 4 + (threadIdx.x >> 6);
    if (node >= n) return;
    int lane = threadIdx.x & 63;
    int half = lane >> 5;
    int l32 = lane & 31;
    int beg = row_ptr[node];
    int end = row_ptr[node + 1];

    float4 ac[8];
    #pragma unroll
    for (int k = 0; k < 8; ++k) ac[k] = make_float4(0.f, 0.f, 0.f, 0.f);

    int j = beg;
    for (; j + 16 <= end; j += 16) {
        int sr[8];
        #pragma unroll
        for (int k = 0; k < 8; ++k) sr[k] = srcs[j + 2 * k + half];
        ushort4 v[8];
        #pragma unroll
        for (int k = 0; k < 8; ++k)
            v[k] = *reinterpret_cast<const ushort4*>(xb + (size_t)sr[k] * D + l32 * 4);
        #pragma unroll
        for (int k = 0; k < 8; ++k) acc_bf(ac[k], v[k]);
    }
    if (j + 8 <= end) {
        int sr[4];
        #pragma unroll
        for (int k = 0; k < 4; ++k) sr[k] = srcs[j + 2 * k + half];
        ushort4 v[4];
        #pragma unroll
        for (int k = 0; k < 4; ++k)
            v[k] = *reinterpret_cast<const ushort4*>(xb + (size_t)sr[k] * D + l32 * 4);
        #pragma unroll
        for (int k = 0; k < 4; ++k) acc_bf(ac[k], v[k]);
        j += 8;
    }
    if (j + 4 <= end) {
        ushort4 v0 = *reinterpret_cast<const ushort4*>(xb + (size_t)srcs[j + half] * D + l32 * 4);
        ushort4 v1 = *reinterpret_cast<const ushort4*>(xb + (size_t)srcs[j + 2 + half] * D + l32 * 4);
        acc_bf(ac[0], v0);
        acc_bf(ac[1], v1);
        j += 4;
    }
    if (j + 2 <= end) {
        ushort4 v0 = *reinterpret_cast<const ushort4*>(xb + (size_t)srcs[j + half] * D + l32 * 4);
        acc_bf(ac[0], v0);
        j += 2;
    }
    if (j < end && half == 0) {
        ushort4 v0 = *reinterpret_cast<const ushort4*>(xb + (size_t)srcs[j] * D + l32 * 4);
        acc_bf(ac[0], v0);
    }
    // reduce 8 chains -> 1
    #pragma unroll
    for (int k = 4; k >= 1; k >>= 1)
        #pragma unroll
        for (int m = 0; m < k; ++m) {
            ac[m].x += ac[m + k].x; ac[m].y += ac[m + k].y;
            ac[m].z += ac[m + k].z; ac[m].w += ac[m + k].w;
        }
    ac[0].x += __shfl_xor(ac[0].x, 32, 64);
    ac[0].y += __shfl_xor(ac[0].y, 32, 64);
    ac[0].z += __shfl_xor(ac[0].z, 32, 64);
    ac[0].w += __shfl_xor(ac[0].w, 32, 64);

    if (half == 0) {
        float inv = 1.0f / fmaxf((float)(end - beg), 1.0f);
        float4 o;
        o.x = ac[0].x * inv; o.y = ac[0].y * inv; o.z = ac[0].z * inv; o.w = ac[0].w * inv;
        *reinterpret_cast<float4*>(mean + (size_t)node * D + l32 * 4) = o;
    }
}

// ---------------- weight prep: split + transpose ----------------
__global__ __launch_bounds__(256) void split_w(const float* __restrict__ w1l,
                                               const float* __restrict__ w1r,
                                               const float* __restrict__ w2l,
                                               const float* __restrict__ w2r,
                                               short* __restrict__ wt) {
    int b = blockIdx.x;           // 0..255 = layer*128 + n
    int layer = b >> 7;
    int nn = b & 127;
    int k = threadIdx.x;          // 0..255
    const float* wl = layer ? w2l : w1l;
    const float* wr = layer ? w2r : w1r;
    float v = (k < 128) ? wl[k * D + nn] : wr[(k - 128) * D + nn];
    unsigned short h = f2bf_rne(v);
    float lo = v - bf2f(h);
    unsigned short l = f2bf_rne(lo);
    short* base = wt + layer * 65536;
    base[nn * 256 + k] = (short)h;
    base[32768 + nn * 256 + k] = (short)l;
}

// ---------------- MFMA dual-GEMM + bias + relu (transposed-output epilogue) ----
// acc = mfma(B_frag, A_frag) computes (A@B)^T fragments:
//   lane&15 = C row (within 16-row frag), kg*4+reg = C col -> float4 stores.
__global__ __launch_bounds__(256, 2) void sage_mm_mfma(
    const float* __restrict__ mean, const float* __restrict__ xin,
    const short* __restrict__ wth, const short* __restrict__ wtl,
    const float* __restrict__ bias, float* __restrict__ out,
    unsigned short* __restrict__ hbout, int n) {
    __shared__ short sAh[128 * 40];
    __shared__ short sAl[128 * 40];
    __shared__ short sBh[128 * 40];
    __shared__ short sBl[128 * 40];
    const int tid = threadIdx.x;
    const int wave = tid >> 6;
    const int lane = tid & 63;
    const int l15 = lane & 15;
    const int kg = lane >> 4;
    const int row0 = blockIdx.x * BM;

    f32x4 acc[2][8];
    #pragma unroll
    for (int fr = 0; fr < 2; ++fr)
        #pragma unroll
        for (int fc = 0; fc < 8; ++fc)
            acc[fr][fc] = (f32x4){0.f, 0.f, 0.f, 0.f};

    float4 pa[4];
    int4 pbh[2], pbl[2];

    #pragma unroll
    for (int i = 0; i < 4; ++i) {
        int f = tid + i * 256;
        int row = f >> 3, k4 = f & 7;
        int gr = row0 + row;
        pa[i] = (gr < n) ? *reinterpret_cast<const float4*>(&mean[(size_t)gr * D + k4 * 4])
                         : make_float4(0.f, 0.f, 0.f, 0.f);
    }
    #pragma unroll
    for (int i = 0; i < 2; ++i) {
        int f = tid + i * 256;
        int n_ = f >> 2, kq = f & 3;
        pbh[i] = *reinterpret_cast<const int4*>(&wth[n_ * 256 + kq * 8]);
        pbl[i] = *reinterpret_cast<const int4*>(&wtl[n_ * 256 + kq * 8]);
    }

    for (int c = 0; c < 8; ++c) {
        #pragma unroll
        for (int i = 0; i < 4; ++i) {
            int f = tid + i * 256;
            int row = f >> 3, k4 = f & 7;
            const float* pv = &pa[i].x;
            unsigned short h[4], l[4];
            #pragma unroll
            for (int j = 0; j < 4; ++j) {
                float v = pv[j];
                h[j] = f2bf_rne(v);
                l[j] = f2bf_rne(v - bf2f(h[j]));
            }
            short* dsth = &sAh[row * 40 + k4 * 4];
            short* dstl = &sAl[row * 40 + k4 * 4];
            #pragma unroll
            for (int j = 0; j < 4; ++j) { dsth[j] = (short)h[j]; dstl[j] = (short)l[j]; }
        }
        #pragma unroll
        for (int i = 0; i < 2; ++i) {
            int f = tid + i * 256;
            int n_ = f >> 2, kq = f & 3;
            *reinterpret_cast<int4*>(&sBh[n_ * 40 + kq * 8]) = pbh[i];
            *reinterpret_cast<int4*>(&sBl[n_ * 40 + kq * 8]) = pbl[i];
        }
        __syncthreads();

        if (c < 7) {
            const float* __restrict__ anext = (c + 1 < 4) ? mean : xin;
            const int ka = ((c + 1) & 3) * 32;
            const int kb = (c + 1) * 32;
            #pragma unroll
            for (int i = 0; i < 4; ++i) {
                int f = tid + i * 256;
                int row = f >> 3, k4 = f & 7;
                int gr = row0 + row;
                pa[i] = (gr < n) ? *reinterpret_cast<const float4*>(&anext[(size_t)gr * D + ka + k4 * 4])
                                 : make_float4(0.f, 0.f, 0.f, 0.f);
            }
            #pragma unroll
            for (int i = 0; i < 2; ++i) {
                int f = tid + i * 256;
                int n_ = f >> 2, kq = f & 3;
                pbh[i] = *reinterpret_cast<const int4*>(&wth[n_ * 256 + kb + kq * 8]);
                pbl[i] = *reinterpret_cast<const int4*>(&wtl[n_ * 256 + kb + kq * 8]);
            }
        }

        short8 ah[2], al[2];
        #pragma unroll
        for (int fr = 0; fr < 2; ++fr) {
            int r = wave * 32 + fr * 16 + l15;
            ah[fr] = *reinterpret_cast<const short8*>(&sAh[r * 40 + kg * 8]);
            al[fr] = *reinterpret_cast<const short8*>(&sAl[r * 40 + kg * 8]);
        }
        #pragma unroll
        for (int fc = 0; fc < 8; ++fc) {
            int cc = fc * 16 + l15;
            short8 bh = *reinterpret_cast<const short8*>(&sBh[cc * 40 + kg * 8]);
            short8 bl = *reinterpret_cast<const short8*>(&sBl[cc * 40 + kg * 8]);
            #pragma unroll
            for (int fr = 0; fr < 2; ++fr) {
                // (A@B)^T = B^T@A^T : pass B-frag as operand 1
                acc[fr][fc] = __builtin_amdgcn_mfma_f32_16x16x32_bf16(bh, ah[fr], acc[fr][fc], 0, 0, 0);
                acc[fr][fc] = __builtin_amdgcn_mfma_f32_16x16x32_bf16(bh, al[fr], acc[fr][fc], 0, 0, 0);
                acc[fr][fc] = __builtin_amdgcn_mfma_f32_16x16x32_bf16(bl, ah[fr], acc[fr][fc], 0, 0, 0);
            }
        }
        __syncthreads();
    }

    // epilogue: lane = C row (l15), cols = fc*16 + kg*4 + 0..3 -> float4 stores
    float4 b4[8];
    #pragma unroll
    for (int fc = 0; fc < 8; ++fc)
        b4[fc] = *reinterpret_cast<const float4*>(&bias[fc * 16 + kg * 4]);
    #pragma unroll
    for (int fr = 0; fr < 2; ++fr) {
        int gr = row0 + wave * 32 + fr * 16 + l15;
        if (gr < n) {
            #pragma unroll
            for (int fc = 0; fc < 8; ++fc) {
                float4 o;
                o.x = fmaxf(acc[fr][fc][0] + b4[fc].x, 0.f);
                o.y = fmaxf(acc[fr][fc][1] + b4[fc].y, 0.f);
                o.z = fmaxf(acc[fr][fc][2] + b4[fc].z, 0.f);
                o.w = fmaxf(acc[fr][fc][3] + b4[fc].w, 0.f);
                *reinterpret_cast<float4*>(&out[(size_t)gr * D + fc * 16 + kg * 4]) = o;
                if (hbout) {
                    ushort4 u;
                    u.x = f2bf_rne(o.x); u.y = f2bf_rne(o.y);
                    u.z = f2bf_rne(o.z); u.w = f2bf_rne(o.w);
                    *reinterpret_cast<ushort4*>(&hbout[(size_t)gr * D + fc * 16 + kg * 4]) = u;
                }
            }
        }
    }
}

// ---------------- launch ----------------

extern "C" void kernel_launch(void* const* d_in, const int* in_sizes, int n_in,
                              void* d_out, int out_size, void* d_ws, size_t ws_size,
                              hipStream_t stream) {
    const float* x   = (const float*)d_in[0];
    const int*   ei  = (const int*)d_in[1];
    const float* w1l = (const float*)d_in[2];
    const float* b1l = (const float*)d_in[3];
    const float* w1r = (const float*)d_in[4];
    const float* w2l = (const float*)d_in[5];
    const float* b2l = (const float*)d_in[6];
    const float* w2r = (const float*)d_in[7];
    float* out = (float*)d_out;

    const int n = in_sizes[0] / D;   // 100000
    const int e = in_sizes[1] / 2;   // 1600000
    const int* rowi = ei;            // sources
    const int* coli = ei + e;        // targets

    const int nbkt = (n + 255) >> 8;          // 391 (<=512)
    const int n2 = nbkt * NWG;                // 100096
    const int cpw = (e + NWG - 1) / NWG;      // 6250
    const int nb2 = n2 / 256;                 // 391
    const int PN = ((n + 1 + 63) / 64) * 64;
    const int total = n * D;                  // 12,800,000

    int* row_ptr  = (int*)d_ws;               // PN
    int* hist_t   = row_ptr + PN;             // n2
    int* scanned  = hist_t + n2;              // n2
    int* bsum     = scanned + n2;             // 512
    int* srcs     = bsum + 512;               // e
    short* wt     = (short*)(srcs + e);       // 4 * 32768 shorts (256KB)
    float* mean   = (float*)(wt + 4 * 32768); // n*D floats
    unsigned short* xhb = (unsigned short*)(mean + (size_t)total); // n*D bf16
    unsigned int* ebuf  = (unsigned int*)mean; // e (aliased; dead before agg)

    // x -> bf16 plane (xhb); also reused for h after layer-1 mm
    convert_x<<<(total / 8 + 255) / 256, 256, 0, stream>>>(x, xhb, total);
    split_w<<<256, 256, 0, stream>>>(w1l, w1r, w2l, w2r, wt);

    hist_bucket<<<NWG, 256, 0, stream>>>(coli, hist_t, e, nbkt, cpw);
    scan1<<<nb2, 256, 0, stream>>>(hist_t, scanned, bsum, n2);
    scan2<<<1, 512, 0, stream>>>(bsum, nb2);
    scan3b<<<nb2, 256, 0, stream>>>(scanned, bsum, n2);
    scatter_bucket<<<NWG, 256, 0, stream>>>(rowi, coli, scanned, ebuf, e, nbkt, cpw);
    csr_bucket<<<nbkt, 256, 0, stream>>>(scanned, ebuf, row_ptr, srcs, e, n, nbkt);
    set_end<<<1, 1, 0, stream>>>(row_ptr, n, e);

    const int mm_grid = (n + BM - 1) / BM;

    // layer 1: h = relu(mean(x)@w1l + b1l + x@w1r); h fp32 in d_out, bf16 in xhb
    aggregate_mean_bf16<<<(n + 3) / 4, 256, 0, stream>>>(xhb, mean, row_ptr, srcs, n);
    sage_mm_mfma<<<mm_grid, 256, 0, stream>>>(mean, x, wt, wt + 32768, b1l, out, xhb, n);

    // layer 2: out = relu(mean(h)@w2l + b2l + h@w2r), in place over h
    aggregate_mean_bf16<<<(n + 3) / 4, 256, 0, stream>>>(xhb, mean, row_ptr, srcs, n);
    sage_mm_mfma<<<mm_grid, 256, 0, stream>>>(mean, out, wt + 65536, wt + 98304, b2l, out, nullptr, n);
}